// Round 2
// baseline (108.127 us; speedup 1.0000x reference)
//
#include <hip/hip_runtime.h>

// PhiRestraint: masked sum over (B,P) of cubic-spline(angle at x_CB between
// (x_CA - x_CB) and (y_CB - x_CB)), spline interval by searchsorted(cutoffs, phi).
// B=8, L=512, P=80000, K=16 knots -> 15 intervals.
//
// Layout choice: tid = p*8 + b so the 8 batch-items of one pair occupy 8
// consecutive lanes -> their 16B gathers into the same 240B coeff row merge
// in the per-instruction coalescer (~4 lines/8 lanes instead of 8+).

namespace {
constexpr int BATCH = 8;
constexpr int SEQL  = 512;
constexpr int NPAIR = 80000;
constexpr int NKNOT = 16;
constexpr int NINT  = 15;
constexpr int BLOCK = 256;
constexpr int TOTAL = BATCH * NPAIR;     // 640000
constexpr int NBLK  = TOTAL / BLOCK;     // 2500 exactly
}

__device__ inline float block_reduce_sum(float v) {
    __shared__ float lds[BLOCK / 64];
    #pragma unroll
    for (int o = 32; o > 0; o >>= 1) v += __shfl_down(v, o, 64);
    const int wave = threadIdx.x >> 6;
    const int lane = threadIdx.x & 63;
    if (lane == 0) lds[wave] = v;
    __syncthreads();
    if (wave == 0) {
        v = (lane < BLOCK / 64) ? lds[lane] : 0.0f;
        #pragma unroll
        for (int o = BLOCK / 128; o > 0; o >>= 1) v += __shfl_down(v, o, 64);
    }
    return v;  // valid in thread 0
}

__global__ __launch_bounds__(BLOCK) void phi_main_kernel(
    const float* __restrict__ CA, const float* __restrict__ CB,
    const float* __restrict__ coeff, const float* __restrict__ cutoffs,
    const int* __restrict__ x_idx, const int* __restrict__ y_idx,
    float* __restrict__ partial)
{
    const int tid = blockIdx.x * BLOCK + threadIdx.x;  // = p*8 + b
    const int p = tid >> 3;
    const int b = tid & 7;

    // 8 consecutive lanes share p -> these dword loads coalesce (8 distinct
    // dwords per 64 lanes).
    const int xi = x_idx[p];
    const int yi = y_idx[p];

    const float* pxa = CA + (size_t)(b * SEQL + xi) * 3;
    const float* pxb = CB + (size_t)(b * SEQL + xi) * 3;
    const float* pyb = CB + (size_t)(b * SEQL + yi) * 3;

    const float xax = pxa[0], xay = pxa[1], xaz = pxa[2];
    const float xbx = pxb[0], xby = pxb[1], xbz = pxb[2];
    const float ybx = pyb[0], yby = pyb[1], ybz = pyb[2];

    // x = x_CA - x_CB ; y = y_CB - x_CB
    const float xx = xax - xbx, xy = xay - xby, xz = xaz - xbz;
    const float yx = ybx - xbx, yy = yby - xby, yz = ybz - xbz;

    const float nx = sqrtf(xx * xx + xy * xy + xz * xz);
    const float ny = sqrtf(yx * yx + yy * yy + yz * yz);

    const float eps = 1e-6f;
    const bool valid = (nx > eps) && (ny > eps);
    const float denom = valid ? nx * ny : 1.0f;
    const float c = (xx * yx + xy * yy + xz * yz) / denom;
    const bool good = (1.0f - c * c) > eps;
    const bool m = valid && good;

    float acc = 0.0f;
    if (m) {
        const float clip_hi = 1.0f - 1e-7f;  // f32(1-1e-7) == 0x3F7FFFFE
        const float cl = fminf(fmaxf(c, -clip_hi), clip_hi);
        const float phi = acosf(cl);

        // searchsorted(cutoffs, phi, side='left') = #elements strictly < phi.
        // cutoffs values are wave-uniform (scalar loads); track the largest
        // cutoff < phi so no dependent cutoffs[idx] reload is needed.
        // phi in (0, pi]; cutoffs[0] ~ -0.39 < phi, cutoffs[15] ~ pi+0.39 > phi
        // -> cnt in [1,15], so low == cutoffs[clip(cnt-1,0,14)] exactly.
        int cnt = 0;
        float low = cutoffs[0];
        #pragma unroll
        for (int k = 0; k < NKNOT; ++k) {
            const float ck = cutoffs[k];
            const bool lt = ck < phi;
            cnt += lt ? 1 : 0;
            low = lt ? ck : low;
        }
        int idx = cnt - 1;
        idx = idx < 0 ? 0 : (idx > NINT - 1 ? NINT - 1 : idx);

        const float dx = phi - low;

        // 16B-aligned gather of the selected interval's 4 poly coeffs.
        const float4 cf = *reinterpret_cast<const float4*>(
            coeff + ((size_t)(xi * SEQL + yi) * NINT + idx) * 4);

        // c3 + dx*(c2 + dx*(c1 + dx*c0))
        acc = cf.w + dx * (cf.z + dx * (cf.y + dx * cf.x));
    }

    const float bsum = block_reduce_sum(acc);
    if (threadIdx.x == 0) partial[blockIdx.x] = bsum;
}

__global__ __launch_bounds__(BLOCK) void phi_reduce_kernel(
    const float* __restrict__ partial, float* __restrict__ out)
{
    float v = 0.0f;
    for (int i = threadIdx.x; i < NBLK; i += BLOCK) v += partial[i];
    const float total = block_reduce_sum(v);
    if (threadIdx.x == 0) out[0] = total;
}

extern "C" void kernel_launch(void* const* d_in, const int* in_sizes, int n_in,
                              void* d_out, int out_size, void* d_ws, size_t ws_size,
                              hipStream_t stream) {
    const float* CA      = (const float*)d_in[0];
    const float* CB      = (const float*)d_in[1];
    const float* coeff   = (const float*)d_in[2];
    const float* cutoffs = (const float*)d_in[3];
    const int*   x_idx   = (const int*)d_in[4];
    const int*   y_idx   = (const int*)d_in[5];
    float* out = (float*)d_out;
    float* partial = (float*)d_ws;  // NBLK floats = 10 KB scratch

    phi_main_kernel<<<NBLK, BLOCK, 0, stream>>>(CA, CB, coeff, cutoffs,
                                                x_idx, y_idx, partial);
    phi_reduce_kernel<<<1, BLOCK, 0, stream>>>(partial, out);
}

// Round 4
// 106.964 us; speedup vs baseline: 1.0109x; 1.0109x over previous
//
#include <hip/hip_runtime.h>

// PhiRestraint: masked sum over (B,P) of cubic-spline(angle at x_CB between
// (x_CA - x_CB) and (y_CB - x_CB)), interval by searchsorted(cutoffs, phi).
// B=8, L=512, P=80000, K=16 knots -> 15 intervals.
//
// R2/R3: stage u = CA-CB (exact same f32 subtract as reference) and CB in LDS
// ([r][b][3] layout -> 8-lane batch-groups hit distinct banks; the four
// xi%4 residue classes own disjoint bank sets). 256 blocks x 1024 threads,
// 96 KB LDS (1 block/CU), 3 grid-stride items/thread for ILP on the
// L3-resident coeff gathers. Item index = p*8+b so the 8 batches of a pair
// sit in consecutive lanes and their 16B coeff gathers coalesce into the
// same 240B row.

namespace {
constexpr int BATCH = 8;
constexpr int SEQL  = 512;
constexpr int NPAIR = 80000;
constexpr int NKNOT = 16;
constexpr int NINT  = 15;
constexpr int BLOCK = 1024;
constexpr int GRID  = 256;                 // 1 block per CU
constexpr int TOTAL = BATCH * NPAIR;       // 640000
constexpr int STRIDE = BLOCK * GRID;       // 262144
constexpr int NITEM = 3;                   // ceil(TOTAL / STRIDE)
constexpr int NCOORD = SEQL * BATCH * 3;   // 12288 floats per table
}

__device__ inline float block_reduce_sum(float v) {
    __shared__ float red[BLOCK / 64];
    #pragma unroll
    for (int o = 32; o > 0; o >>= 1) v += __shfl_down(v, o, 64);
    const int wave = threadIdx.x >> 6;
    const int lane = threadIdx.x & 63;
    if (lane == 0) red[wave] = v;
    __syncthreads();
    if (wave == 0) {
        v = (lane < BLOCK / 64) ? red[lane] : 0.0f;
        #pragma unroll
        for (int o = BLOCK / 128; o > 0; o >>= 1) v += __shfl_down(v, o, 64);
    }
    return v;  // valid in thread 0
}

__global__ __launch_bounds__(BLOCK) void phi_main_kernel(
    const float* __restrict__ CA, const float* __restrict__ CB,
    const float* __restrict__ coeff, const float* __restrict__ cutoffs,
    const int* __restrict__ x_idx, const int* __restrict__ y_idx,
    float* __restrict__ partial)
{
    // [r][b][3]: an 8-lane group (b=0..7, same r) reads banks r*24+{0..23}
    __shared__ float u_lds [NCOORD];   // CA - CB, 48 KB
    __shared__ float cb_lds[NCOORD];   // CB,      48 KB

    for (int i = threadIdx.x; i < NCOORD; i += BLOCK) {
        const float ca = CA[i];
        const float cb = CB[i];
        const int b    = i / (SEQL * 3);           // const-divisor magic mul
        const int rem  = i - b * (SEQL * 3);
        const int r    = rem / 3;
        const int comp = rem - r * 3;
        const int j    = (r * BATCH + b) * 3 + comp;
        u_lds[j]  = ca - cb;                       // exact f32 sub == reference
        cb_lds[j] = cb;
    }
    __syncthreads();

    const float eps = 1e-6f;
    float acc = 0.0f;

    #pragma unroll
    for (int k = 0; k < NITEM; ++k) {
        const int item = blockIdx.x * BLOCK + threadIdx.x + k * STRIDE; // = p*8+b
        if (item < TOTAL) {
            const int p = item >> 3;
            const int b = item & 7;
            const int xi = x_idx[p];   // 8 lanes share p -> coalesced
            const int yi = y_idx[p];

            const float* pu  = &u_lds [(xi * BATCH + b) * 3];
            const float* pxb = &cb_lds[(xi * BATCH + b) * 3];
            const float* pyb = &cb_lds[(yi * BATCH + b) * 3];

            const float xx = pu[0],  xy = pu[1],  xz = pu[2];
            const float xbx = pxb[0], xby = pxb[1], xbz = pxb[2];
            const float ybx = pyb[0], yby = pyb[1], ybz = pyb[2];

            const float yx = ybx - xbx, yy = yby - xby, yz = ybz - xbz;

            const float nx = sqrtf(xx * xx + xy * xy + xz * xz);
            const float ny = sqrtf(yx * yx + yy * yy + yz * yz);

            const bool valid = (nx > eps) && (ny > eps);
            const float denom = valid ? nx * ny : 1.0f;
            const float c = (xx * yx + xy * yy + xz * yz) / denom;
            const bool good = (1.0f - c * c) > eps;
            const bool m = valid && good;

            if (m) {
                const float clip_hi = 1.0f - 1e-7f;  // f32(1-1e-7) == 0x3F7FFFFE
                const float cl = fminf(fmaxf(c, -clip_hi), clip_hi);
                const float phi = acosf(cl);

                // searchsorted(cutoffs, phi, 'left') = #cutoffs strictly < phi.
                // Track the largest cutoff < phi: phi in (0,pi], cutoffs span
                // [-0.39, pi+0.39] -> cnt in [1,15], low == cutoffs[clip(cnt-1)].
                int cnt = 0;
                float low = cutoffs[0];
                #pragma unroll
                for (int t = 0; t < NKNOT; ++t) {
                    const float ck = cutoffs[t];   // wave-uniform scalar loads
                    const bool lt = ck < phi;
                    cnt += lt ? 1 : 0;
                    low = lt ? ck : low;
                }
                int idx = cnt - 1;
                idx = idx < 0 ? 0 : (idx > NINT - 1 ? NINT - 1 : idx);

                const float dx = phi - low;

                // 16B-aligned gather from the 63 MB (L3-resident) coeff table
                const float4 cf = *reinterpret_cast<const float4*>(
                    coeff + ((size_t)(xi * SEQL + yi) * NINT + idx) * 4);

                // c3 + dx*(c2 + dx*(c1 + dx*c0))
                acc += cf.w + dx * (cf.z + dx * (cf.y + dx * cf.x));
            }
        }
    }

    const float bsum = block_reduce_sum(acc);
    if (threadIdx.x == 0) partial[blockIdx.x] = bsum;
}

__global__ __launch_bounds__(256) void phi_reduce_kernel(
    const float* __restrict__ partial, float* __restrict__ out)
{
    float v = (threadIdx.x < GRID) ? partial[threadIdx.x] : 0.0f;
    #pragma unroll
    for (int o = 32; o > 0; o >>= 1) v += __shfl_down(v, o, 64);
    __shared__ float red[4];
    const int wave = threadIdx.x >> 6;
    const int lane = threadIdx.x & 63;
    if (lane == 0) red[wave] = v;
    __syncthreads();
    if (threadIdx.x == 0) out[0] = red[0] + red[1] + red[2] + red[3];
}

extern "C" void kernel_launch(void* const* d_in, const int* in_sizes, int n_in,
                              void* d_out, int out_size, void* d_ws, size_t ws_size,
                              hipStream_t stream) {
    const float* CA      = (const float*)d_in[0];
    const float* CB      = (const float*)d_in[1];
    const float* coeff   = (const float*)d_in[2];
    const float* cutoffs = (const float*)d_in[3];
    const int*   x_idx   = (const int*)d_in[4];
    const int*   y_idx   = (const int*)d_in[5];
    float* out = (float*)d_out;
    float* partial = (float*)d_ws;   // GRID floats = 1 KB scratch

    phi_main_kernel<<<GRID, BLOCK, 0, stream>>>(CA, CB, coeff, cutoffs,
                                                x_idx, y_idx, partial);
    phi_reduce_kernel<<<1, 256, 0, stream>>>(partial, out);
}